// Round 1
// baseline (1271.723 us; speedup 1.0000x reference)
//
#include <hip/hip_runtime.h>

#define NEG_SLOPE 0.2f
#define EPSV 1e-16f

// ---------------------------------------------------------------------------
// CSR build (by destination node), self-loops appended after the E real edges
// ---------------------------------------------------------------------------
__global__ __launch_bounds__(256)
void count_kernel(const int* __restrict__ ei, int* __restrict__ deg, int E, int n) {
    int i = blockIdx.x * blockDim.x + threadIdx.x;
    int M = E + n;
    if (i >= M) return;
    int d = (i < E) ? ei[E + i] : (i - E);
    atomicAdd(&deg[d], 1);
}

__global__ __launch_bounds__(1024)
void scan_kernel(const int* __restrict__ deg, int* __restrict__ indptr, int n) {
    __shared__ int wsum[16];
    __shared__ int carry_s;
    const int t = threadIdx.x;
    const int lane = t & 63;
    const int w = t >> 6;
    if (t == 0) carry_s = 0;
    __syncthreads();
    for (int base = 0; base < n; base += 1024) {
        int i = base + t;
        int v = (i < n) ? deg[i] : 0;
        int s = v;
        #pragma unroll
        for (int off = 1; off < 64; off <<= 1) {
            int u = __shfl_up(s, off);
            if (lane >= off) s += u;
        }
        if (lane == 63) wsum[w] = s;
        __syncthreads();
        if (w == 0 && lane < 16) {
            int ws_ = wsum[lane];
            #pragma unroll
            for (int off = 1; off < 16; off <<= 1) {
                int u = __shfl_up(ws_, off);
                if (lane >= off) ws_ += u;
            }
            wsum[lane] = ws_;
        }
        __syncthreads();
        int woff = (w > 0) ? wsum[w - 1] : 0;
        int total = wsum[15];
        int carry = carry_s;
        if (i < n) indptr[i + 1] = carry + woff + s;
        __syncthreads();
        if (t == 0) carry_s = carry + total;
        __syncthreads();
    }
    if (t == 0) indptr[0] = 0;
}

__global__ __launch_bounds__(256)
void scatter_kernel(const int* __restrict__ ei, int* __restrict__ cursor,
                    int* __restrict__ csr_src, int E, int n) {
    int i = blockIdx.x * blockDim.x + threadIdx.x;
    int M = E + n;
    if (i >= M) return;
    int s, d;
    if (i < E) { s = ei[i]; d = ei[E + i]; }
    else       { s = i - E; d = i - E; }
    int pos = atomicAdd(&cursor[d], 1);
    csr_src[pos] = s;
}

// ---------------------------------------------------------------------------
// Tiled fp32 GEMM: C[M,N] = A[M,K] @ B[K,N].  K % 16 == 0, N % 64 == 0.
// ---------------------------------------------------------------------------
constexpr int GBM = 64, GBN = 64, GBK = 16;

__global__ __launch_bounds__(256)
void gemm_kernel(const float* __restrict__ A, const float* __restrict__ B,
                 float* __restrict__ C, int M, int K, int N) {
    __shared__ float As[GBK][GBM + 4];
    __shared__ float Bs[GBK][GBN];
    const int tid = threadIdx.x;
    const int tr = tid >> 4;   // 0..15
    const int tc = tid & 15;   // 0..15
    const int row0 = blockIdx.x * GBM;
    const int col0 = blockIdx.y * GBN;
    float acc[4][4] = {};
    for (int k0 = 0; k0 < K; k0 += GBK) {
        #pragma unroll
        for (int it = 0; it < (GBM * GBK) / 256; ++it) {
            int idx = tid + it * 256;
            int r = idx >> 4;
            int kk = idx & 15;
            int gr = row0 + r;
            As[kk][r] = (gr < M) ? A[(long)gr * K + k0 + kk] : 0.f;
        }
        #pragma unroll
        for (int it = 0; it < (GBK * GBN) / 256; ++it) {
            int idx = tid + it * 256;
            int kk = idx >> 6;
            int c = idx & 63;
            Bs[kk][c] = B[(long)(k0 + kk) * N + col0 + c];
        }
        __syncthreads();
        #pragma unroll
        for (int kk = 0; kk < GBK; ++kk) {
            float a[4], b[4];
            #pragma unroll
            for (int i = 0; i < 4; ++i) a[i] = As[kk][tr * 4 + i];
            #pragma unroll
            for (int j = 0; j < 4; ++j) b[j] = Bs[kk][tc * 4 + j];
            #pragma unroll
            for (int i = 0; i < 4; ++i)
                #pragma unroll
                for (int j = 0; j < 4; ++j)
                    acc[i][j] += a[i] * b[j];
        }
        __syncthreads();
    }
    #pragma unroll
    for (int i = 0; i < 4; ++i) {
        int gr = row0 + tr * 4 + i;
        if (gr < M) {
            #pragma unroll
            for (int j = 0; j < 4; ++j)
                C[(long)gr * N + col0 + tc * 4 + j] = acc[i][j];
        }
    }
}

// ---------------------------------------------------------------------------
// alpha_src[n,h] = sum_c h[n,h,c]*a_src[h,c]  (wave per node, C=64 fixed)
// ---------------------------------------------------------------------------
__global__ __launch_bounds__(256)
void alpha_kernel(const float* __restrict__ h, const float* __restrict__ a_src,
                  const float* __restrict__ a_dst, float* __restrict__ asrc,
                  float* __restrict__ adst, int n, int H) {
    int wid = (blockIdx.x * blockDim.x + threadIdx.x) >> 6;
    int lane = threadIdx.x & 63;
    if (wid >= n) return;
    const int HC = H * 64;
    for (int hd = 0; hd < H; ++hd) {
        float v = h[(long)wid * HC + hd * 64 + lane];
        float s = v * a_src[hd * 64 + lane];
        float d = v * a_dst[hd * 64 + lane];
        #pragma unroll
        for (int off = 32; off > 0; off >>= 1) {
            s += __shfl_down(s, off);
            d += __shfl_down(d, off);
        }
        if (lane == 0) {
            asrc[wid * H + hd] = s;
            adst[wid * H + hd] = d;
        }
    }
}

// ---------------------------------------------------------------------------
// Per-(node, head) softmax-weighted aggregation. Wave = 64 lanes = channels.
// ---------------------------------------------------------------------------
__global__ __launch_bounds__(256)
void aggregate_kernel(const float* __restrict__ h, const float* __restrict__ asrc,
                      const float* __restrict__ adst, const int* __restrict__ indptr,
                      const int* __restrict__ csr_src, const float* __restrict__ bias,
                      float* __restrict__ out, int n, int H, int apply_elu) {
    int wid = (blockIdx.x * blockDim.x + threadIdx.x) >> 6;
    int lane = threadIdx.x & 63;
    int node = wid / H;
    int hd = wid - node * H;
    if (node >= n) return;
    const int HC = H * 64;
    const int beg = indptr[node];
    const int end = indptr[node + 1];
    const float ad = adst[node * H + hd];

    // pass 1: max over incoming edges (lane-parallel)
    float m = -3.4e38f;
    for (int i = beg + lane; i < end; i += 64) {
        int s = csr_src[i];
        float e = asrc[s * H + hd] + ad;
        e = e > 0.f ? e : NEG_SLOPE * e;
        m = fmaxf(m, e);
    }
    #pragma unroll
    for (int off = 32; off > 0; off >>= 1)
        m = fmaxf(m, __shfl_xor(m, off));

    // pass 2: sequential edges; lane = channel
    float acc = 0.f, sum_ex = 0.f;
    for (int i = beg; i < end; ++i) {
        int s = csr_src[i];
        float e = asrc[s * H + hd] + ad;
        e = e > 0.f ? e : NEG_SLOPE * e;
        float ex = __expf(e - m);
        sum_ex += ex;
        acc += ex * h[(long)s * HC + hd * 64 + lane];
    }
    float o = acc / (sum_ex + EPSV) + bias[hd * 64 + lane];
    if (apply_elu) o = o > 0.f ? o : expm1f(o);
    out[(long)node * HC + hd * 64 + lane] = o;
}

// ---------------------------------------------------------------------------
// Global mean pool (batch is sorted) + classifier
// ---------------------------------------------------------------------------
constexpr int POOL_CHUNK = 128;

__global__ __launch_bounds__(64)
void pool_kernel(const float* __restrict__ h, const int* __restrict__ batch,
                 float* __restrict__ sums, int* __restrict__ counts, int n) {
    int lane = threadIdx.x;
    int start = blockIdx.x * POOL_CHUNK;
    if (start >= n) return;
    int end = min(start + POOL_CHUNK, n);
    int gcur = batch[start];
    float acc = 0.f;
    int run = 0;
    for (int i = start; i < end; ++i) {
        int g = batch[i];
        if (g != gcur) {
            atomicAdd(&sums[gcur * 64 + lane], acc);
            if (lane == 0) atomicAdd(&counts[gcur], run);
            acc = 0.f; run = 0; gcur = g;
        }
        acc += h[(long)i * 64 + lane];
        ++run;
    }
    atomicAdd(&sums[gcur * 64 + lane], acc);
    if (lane == 0) atomicAdd(&counts[gcur], run);
}

__global__ void classify_kernel(const float* __restrict__ sums, const int* __restrict__ counts,
                                const float* __restrict__ Wc, const float* __restrict__ bc,
                                float* __restrict__ out, int G) {
    int t = threadIdx.x;
    if (t >= G * 10) return;
    int g = t / 10, o = t - g * 10;
    int c_ = counts[g];
    float inv = 1.f / (float)(c_ > 1 ? c_ : 1);
    float acc = bc[o];
    for (int c = 0; c < 64; ++c)
        acc += sums[g * 64 + c] * inv * Wc[c * 10 + o];
    out[t] = acc;
}

// ---------------------------------------------------------------------------
extern "C" void kernel_launch(void* const* d_in, const int* in_sizes, int n_in,
                              void* d_out, int out_size, void* d_ws, size_t ws_size,
                              hipStream_t stream) {
    const float* x   = (const float*)d_in[0];
    const int*   ei  = (const int*)d_in[1];
    const int*   bat = (const int*)d_in[2];
    const float* W1  = (const float*)d_in[3];
    const float* as1 = (const float*)d_in[4];
    const float* ad1 = (const float*)d_in[5];
    const float* b1  = (const float*)d_in[6];
    const float* W2  = (const float*)d_in[7];
    const float* as2 = (const float*)d_in[8];
    const float* ad2 = (const float*)d_in[9];
    const float* b2  = (const float*)d_in[10];
    const float* W3  = (const float*)d_in[11];
    const float* as3 = (const float*)d_in[12];
    const float* ad3 = (const float*)d_in[13];
    const float* b3  = (const float*)d_in[14];
    const float* Wc  = (const float*)d_in[15];
    const float* bc  = (const float*)d_in[16];
    float* out = (float*)d_out;

    const int N = in_sizes[2];          // 50000 nodes
    const int E = in_sizes[1] / 2;      // 800000 edges
    const int M = E + N;                // + self loops
    const int IN_C = in_sizes[0] / N;   // 128
    const int G = out_size / 10;        // 64 graphs

    // -------- workspace carve (256B aligned) --------
    char* p = (char*)d_ws;
    auto carve = [&](size_t bytes) -> void* {
        void* r = (void*)p;
        p += (bytes + 255) & ~(size_t)255;
        return r;
    };
    float* hA   = (float*)carve((size_t)N * 256 * 4);
    float* hB   = (float*)carve((size_t)N * 256 * 4);
    float* asrc = (float*)carve((size_t)N * 4 * 4);
    float* adst = (float*)carve((size_t)N * 4 * 4);
    float* sums = (float*)carve((size_t)G * 64 * 4);
    int*   cnts = (int*)carve((size_t)G * 4);
    int*   deg  = (int*)carve((size_t)N * 4);      // reused as scatter cursor
    int*   iptr = (int*)carve((size_t)(N + 1) * 4);
    int*   csr  = (int*)carve((size_t)M * 4);
    (void)ws_size; (void)n_in;

    // -------- CSR build (shared by all 3 layers) --------
    hipMemsetAsync(deg, 0, (size_t)N * 4, stream);
    count_kernel<<<(M + 255) / 256, 256, 0, stream>>>(ei, deg, E, N);
    scan_kernel<<<1, 1024, 0, stream>>>(deg, iptr, N);
    hipMemcpyAsync(deg, iptr, (size_t)N * 4, hipMemcpyDeviceToDevice, stream);
    scatter_kernel<<<(M + 255) / 256, 256, 0, stream>>>(ei, deg, csr, E, N);

    // -------- layer 1: x[N,128] -> hB[N,256] --------
    {
        dim3 grid((N + GBM - 1) / GBM, 256 / GBN);
        gemm_kernel<<<grid, 256, 0, stream>>>(x, W1, hA, N, IN_C, 256);
    }
    alpha_kernel<<<(N + 3) / 4, 256, 0, stream>>>(hA, as1, ad1, asrc, adst, N, 4);
    aggregate_kernel<<<N, 256, 0, stream>>>(hA, asrc, adst, iptr, csr, b1, hB, N, 4, 1);

    // -------- layer 2: hB[N,256] -> hB[N,256] --------
    {
        dim3 grid((N + GBM - 1) / GBM, 256 / GBN);
        gemm_kernel<<<grid, 256, 0, stream>>>(hB, W2, hA, N, 256, 256);
    }
    alpha_kernel<<<(N + 3) / 4, 256, 0, stream>>>(hA, as2, ad2, asrc, adst, N, 4);
    aggregate_kernel<<<N, 256, 0, stream>>>(hA, asrc, adst, iptr, csr, b2, hB, N, 4, 1);

    // -------- layer 3: hB[N,256] -> hB[N,64] (1 head, no ELU) --------
    {
        dim3 grid((N + GBM - 1) / GBM, 64 / GBN);
        gemm_kernel<<<grid, 256, 0, stream>>>(hB, W3, hA, N, 256, 64);
    }
    alpha_kernel<<<(N + 3) / 4, 256, 0, stream>>>(hA, as3, ad3, asrc, adst, N, 1);
    aggregate_kernel<<<(N + 3) / 4, 256, 0, stream>>>(hA, asrc, adst, iptr, csr, b3, hB, N, 1, 0);

    // -------- pool + classify --------
    hipMemsetAsync(sums, 0, (size_t)G * 64 * 4, stream);
    hipMemsetAsync(cnts, 0, (size_t)G * 4, stream);
    pool_kernel<<<(N + POOL_CHUNK - 1) / POOL_CHUNK, 64, 0, stream>>>(hB, bat, sums, cnts, N);
    classify_kernel<<<1, 640, 0, stream>>>(sums, cnts, Wc, bc, out, G);
}

// Round 2
// 903.980 us; speedup vs baseline: 1.4068x; 1.4068x over previous
//
#include <hip/hip_runtime.h>

#define NEG_SLOPE 0.2f
#define EPSV 1e-16f

// ---------------------------------------------------------------------------
// CSR build (by destination node), self-loops appended after the E real edges
// ---------------------------------------------------------------------------
__global__ __launch_bounds__(256)
void count_kernel(const int* __restrict__ ei, int* __restrict__ deg, int E, int n) {
    int i = blockIdx.x * blockDim.x + threadIdx.x;
    int M = E + n;
    if (i >= M) return;
    int d = (i < E) ? ei[E + i] : (i - E);
    atomicAdd(&deg[d], 1);
}

__global__ __launch_bounds__(1024)
void scan_kernel(const int* __restrict__ deg, int* __restrict__ indptr, int n) {
    __shared__ int wsum[16];
    __shared__ int carry_s;
    const int t = threadIdx.x;
    const int lane = t & 63;
    const int w = t >> 6;
    if (t == 0) carry_s = 0;
    __syncthreads();
    for (int base = 0; base < n; base += 1024) {
        int i = base + t;
        int v = (i < n) ? deg[i] : 0;
        int s = v;
        #pragma unroll
        for (int off = 1; off < 64; off <<= 1) {
            int u = __shfl_up(s, off);
            if (lane >= off) s += u;
        }
        if (lane == 63) wsum[w] = s;
        __syncthreads();
        if (w == 0 && lane < 16) {
            int ws_ = wsum[lane];
            #pragma unroll
            for (int off = 1; off < 16; off <<= 1) {
                int u = __shfl_up(ws_, off);
                if (lane >= off) ws_ += u;
            }
            wsum[lane] = ws_;
        }
        __syncthreads();
        int woff = (w > 0) ? wsum[w - 1] : 0;
        int total = wsum[15];
        int carry = carry_s;
        if (i < n) indptr[i + 1] = carry + woff + s;
        __syncthreads();
        if (t == 0) carry_s = carry + total;
        __syncthreads();
    }
    if (t == 0) indptr[0] = 0;
}

__global__ __launch_bounds__(256)
void scatter_kernel(const int* __restrict__ ei, int* __restrict__ cursor,
                    int* __restrict__ csr_src, int E, int n) {
    int i = blockIdx.x * blockDim.x + threadIdx.x;
    int M = E + n;
    if (i >= M) return;
    int s, d;
    if (i < E) { s = ei[i]; d = ei[E + i]; }
    else       { s = i - E; d = i - E; }
    int pos = atomicAdd(&cursor[d], 1);
    csr_src[pos] = s;
}

// ---------------------------------------------------------------------------
// Tiled fp32 GEMM: C[M,N] = A[M,K] @ B[K,N].  K % 16 == 0, N % 64 == 0.
// 128x64 block tile, 256 threads, 8x4 per-thread accumulator.
// ---------------------------------------------------------------------------
constexpr int BM = 128, BN = 64, BK = 16;

__global__ __launch_bounds__(256)
void gemm_kernel(const float* __restrict__ A, const float* __restrict__ B,
                 float* __restrict__ C, int M, int K, int N) {
    __shared__ float As[BK][BM + 4];   // row = 132 floats = 528 B (16B-aligned)
    __shared__ float Bs[BK][BN];       // row = 256 B
    const int tid = threadIdx.x;
    const int tr = tid >> 4;   // 0..15
    const int tc = tid & 15;   // 0..15
    const int row0 = blockIdx.x * BM;
    const int col0 = blockIdx.y * BN;
    float acc[8][4] = {};
    for (int k0 = 0; k0 < K; k0 += BK) {
        #pragma unroll
        for (int it = 0; it < (BM * BK) / 256; ++it) {   // 8
            int idx = tid + it * 256;
            int r = idx >> 4;
            int kk = idx & 15;
            int gr = row0 + r;
            As[kk][r] = (gr < M) ? A[(long)gr * K + k0 + kk] : 0.f;
        }
        #pragma unroll
        for (int it = 0; it < (BK * BN) / 256; ++it) {   // 4
            int idx = tid + it * 256;
            int kk = idx >> 6;
            int c = idx & 63;
            Bs[kk][c] = B[(long)(k0 + kk) * N + col0 + c];
        }
        __syncthreads();
        #pragma unroll
        for (int kk = 0; kk < BK; ++kk) {
            float a[8], b[4];
            #pragma unroll
            for (int i = 0; i < 8; ++i) a[i] = As[kk][tr * 8 + i];
            #pragma unroll
            for (int j = 0; j < 4; ++j) b[j] = Bs[kk][tc * 4 + j];
            #pragma unroll
            for (int i = 0; i < 8; ++i)
                #pragma unroll
                for (int j = 0; j < 4; ++j)
                    acc[i][j] += a[i] * b[j];
        }
        __syncthreads();
    }
    #pragma unroll
    for (int i = 0; i < 8; ++i) {
        int gr = row0 + tr * 8 + i;
        if (gr < M) {
            float4 v = make_float4(acc[i][0], acc[i][1], acc[i][2], acc[i][3]);
            *reinterpret_cast<float4*>(&C[(long)gr * N + col0 + tc * 4]) = v;
        }
    }
}

// ---------------------------------------------------------------------------
// alpha_src[n,h] = sum_c h[n,h,c]*a_src[h,c]  (wave per node, C=64 fixed)
// ---------------------------------------------------------------------------
__global__ __launch_bounds__(256)
void alpha_kernel(const float* __restrict__ h, const float* __restrict__ a_src,
                  const float* __restrict__ a_dst, float* __restrict__ asrc,
                  float* __restrict__ adst, int n, int H) {
    int wid = (blockIdx.x * blockDim.x + threadIdx.x) >> 6;
    int lane = threadIdx.x & 63;
    if (wid >= n) return;
    const int HC = H * 64;
    for (int hd = 0; hd < H; ++hd) {
        float v = h[(long)wid * HC + hd * 64 + lane];
        float s = v * a_src[hd * 64 + lane];
        float d = v * a_dst[hd * 64 + lane];
        #pragma unroll
        for (int off = 32; off > 0; off >>= 1) {
            s += __shfl_down(s, off);
            d += __shfl_down(d, off);
        }
        if (lane == 0) {
            asrc[wid * H + hd] = s;
            adst[wid * H + hd] = d;
        }
    }
}

// ---------------------------------------------------------------------------
// Per-(node, head) softmax-weighted aggregation. Wave = 64 lanes.
// Pass A (lane-parallel, chunk of <=64 edges): gather asrc, leaky-relu,
//   wave-reduced max & sum, exp staged to per-wave LDS slice.
// Pass B (lane = channel): gather h rows, unrolled x4 for MLP.
// Online rescale across chunks (exact; deg>64 is ~nonexistent here).
// ---------------------------------------------------------------------------
__global__ __launch_bounds__(256)
void aggregate_kernel(const float* __restrict__ h, const float* __restrict__ asrc,
                      const float* __restrict__ adst, const int* __restrict__ indptr,
                      const int* __restrict__ csr_src, const float* __restrict__ bias,
                      float* __restrict__ out, int n, int H, int apply_elu) {
    __shared__ int   sInd[4][64];
    __shared__ float sEx[4][64];
    const int wid  = (blockIdx.x * blockDim.x + threadIdx.x) >> 6;
    const int lane = threadIdx.x & 63;
    const int w    = threadIdx.x >> 6;
    const int node = wid / H;
    const int hd   = wid - node * H;
    if (node >= n) return;
    const int HC = H * 64;
    const int beg = indptr[node];
    const int end = indptr[node + 1];
    const float ad = adst[node * H + hd];
    const float* __restrict__ hh = h + hd * 64 + lane;

    float m = -3.4e38f, sum_ex = 0.f, acc = 0.f;
    for (int cb = beg; cb < end; cb += 64) {
        const int cnt = min(64, end - cb);
        // ---- pass A: lane-parallel e/exp over this chunk ----
        int s = 0;
        float e = -3.4e38f;
        if (lane < cnt) {
            s = csr_src[cb + lane];
            e = asrc[s * H + hd] + ad;
            e = e > 0.f ? e : NEG_SLOPE * e;
        }
        float cm = e;
        #pragma unroll
        for (int off = 32; off > 0; off >>= 1) cm = fmaxf(cm, __shfl_xor(cm, off));
        const float nm = fmaxf(m, cm);
        const float scale = __expf(m - nm);        // 0 on the first chunk
        const float ex = (lane < cnt) ? __expf(e - nm) : 0.f;
        float cs = ex;
        #pragma unroll
        for (int off = 32; off > 0; off >>= 1) cs += __shfl_xor(cs, off);
        sum_ex = sum_ex * scale + cs;
        acc *= scale;
        m = nm;
        sInd[w][lane] = s;
        sEx[w][lane]  = ex;
        // wave-private LDS slice: no barrier needed (compiler inserts lgkmcnt)
        // ---- pass B: gather + FMA, unrolled x4 ----
        int i = 0;
        for (; i + 3 < cnt; i += 4) {
            int s0 = sInd[w][i],     s1 = sInd[w][i + 1];
            int s2 = sInd[w][i + 2], s3 = sInd[w][i + 3];
            float e0 = sEx[w][i],     e1 = sEx[w][i + 1];
            float e2 = sEx[w][i + 2], e3 = sEx[w][i + 3];
            float v0 = hh[(long)s0 * HC];
            float v1 = hh[(long)s1 * HC];
            float v2 = hh[(long)s2 * HC];
            float v3 = hh[(long)s3 * HC];
            acc += e0 * v0;
            acc += e1 * v1;
            acc += e2 * v2;
            acc += e3 * v3;
        }
        for (; i < cnt; ++i)
            acc += sEx[w][i] * hh[(long)sInd[w][i] * HC];
    }
    float o = acc / (sum_ex + EPSV) + bias[hd * 64 + lane];
    if (apply_elu) o = o > 0.f ? o : expm1f(o);
    out[(long)node * HC + hd * 64 + lane] = o;
}

// ---------------------------------------------------------------------------
// Global mean pool (batch is sorted) + classifier
// ---------------------------------------------------------------------------
constexpr int POOL_CHUNK = 128;

__global__ __launch_bounds__(64)
void pool_kernel(const float* __restrict__ h, const int* __restrict__ batch,
                 float* __restrict__ sums, int* __restrict__ counts, int n) {
    int lane = threadIdx.x;
    int start = blockIdx.x * POOL_CHUNK;
    if (start >= n) return;
    int end = min(start + POOL_CHUNK, n);
    int gcur = batch[start];
    float acc = 0.f;
    int run = 0;
    for (int i = start; i < end; ++i) {
        int g = batch[i];
        if (g != gcur) {
            atomicAdd(&sums[gcur * 64 + lane], acc);
            if (lane == 0) atomicAdd(&counts[gcur], run);
            acc = 0.f; run = 0; gcur = g;
        }
        acc += h[(long)i * 64 + lane];
        ++run;
    }
    atomicAdd(&sums[gcur * 64 + lane], acc);
    if (lane == 0) atomicAdd(&counts[gcur], run);
}

__global__ void classify_kernel(const float* __restrict__ sums, const int* __restrict__ counts,
                                const float* __restrict__ Wc, const float* __restrict__ bc,
                                float* __restrict__ out, int G) {
    int t = threadIdx.x;
    if (t >= G * 10) return;
    int g = t / 10, o = t - g * 10;
    int c_ = counts[g];
    float inv = 1.f / (float)(c_ > 1 ? c_ : 1);
    float acc = bc[o];
    for (int c = 0; c < 64; ++c)
        acc += sums[g * 64 + c] * inv * Wc[c * 10 + o];
    out[t] = acc;
}

// ---------------------------------------------------------------------------
extern "C" void kernel_launch(void* const* d_in, const int* in_sizes, int n_in,
                              void* d_out, int out_size, void* d_ws, size_t ws_size,
                              hipStream_t stream) {
    const float* x   = (const float*)d_in[0];
    const int*   ei  = (const int*)d_in[1];
    const int*   bat = (const int*)d_in[2];
    const float* W1  = (const float*)d_in[3];
    const float* as1 = (const float*)d_in[4];
    const float* ad1 = (const float*)d_in[5];
    const float* b1  = (const float*)d_in[6];
    const float* W2  = (const float*)d_in[7];
    const float* as2 = (const float*)d_in[8];
    const float* ad2 = (const float*)d_in[9];
    const float* b2  = (const float*)d_in[10];
    const float* W3  = (const float*)d_in[11];
    const float* as3 = (const float*)d_in[12];
    const float* ad3 = (const float*)d_in[13];
    const float* b3  = (const float*)d_in[14];
    const float* Wc  = (const float*)d_in[15];
    const float* bc  = (const float*)d_in[16];
    float* out = (float*)d_out;

    const int N = in_sizes[2];          // 50000 nodes
    const int E = in_sizes[1] / 2;      // 800000 edges
    const int M = E + N;                // + self loops
    const int IN_C = in_sizes[0] / N;   // 128
    const int G = out_size / 10;        // 64 graphs

    // -------- workspace carve (256B aligned) --------
    char* p = (char*)d_ws;
    auto carve = [&](size_t bytes) -> void* {
        void* r = (void*)p;
        p += (bytes + 255) & ~(size_t)255;
        return r;
    };
    float* hA   = (float*)carve((size_t)N * 256 * 4);
    float* hB   = (float*)carve((size_t)N * 256 * 4);
    float* asrc = (float*)carve((size_t)N * 4 * 4);
    float* adst = (float*)carve((size_t)N * 4 * 4);
    float* sums = (float*)carve((size_t)G * 64 * 4);
    int*   cnts = (int*)carve((size_t)G * 4);
    int*   deg  = (int*)carve((size_t)N * 4);      // reused as scatter cursor
    int*   iptr = (int*)carve((size_t)(N + 1) * 4);
    int*   csr  = (int*)carve((size_t)M * 4);
    (void)ws_size; (void)n_in;

    // -------- CSR build (shared by all 3 layers) --------
    hipMemsetAsync(deg, 0, (size_t)N * 4, stream);
    count_kernel<<<(M + 255) / 256, 256, 0, stream>>>(ei, deg, E, N);
    scan_kernel<<<1, 1024, 0, stream>>>(deg, iptr, N);
    hipMemcpyAsync(deg, iptr, (size_t)N * 4, hipMemcpyDeviceToDevice, stream);
    scatter_kernel<<<(M + 255) / 256, 256, 0, stream>>>(ei, deg, csr, E, N);

    // -------- layer 1: x[N,128] -> hB[N,256] --------
    {
        dim3 grid((N + BM - 1) / BM, 256 / BN);
        gemm_kernel<<<grid, 256, 0, stream>>>(x, W1, hA, N, IN_C, 256);
    }
    alpha_kernel<<<(N + 3) / 4, 256, 0, stream>>>(hA, as1, ad1, asrc, adst, N, 4);
    aggregate_kernel<<<N, 256, 0, stream>>>(hA, asrc, adst, iptr, csr, b1, hB, N, 4, 1);

    // -------- layer 2: hB[N,256] -> hB[N,256] --------
    {
        dim3 grid((N + BM - 1) / BM, 256 / BN);
        gemm_kernel<<<grid, 256, 0, stream>>>(hB, W2, hA, N, 256, 256);
    }
    alpha_kernel<<<(N + 3) / 4, 256, 0, stream>>>(hA, as2, ad2, asrc, adst, N, 4);
    aggregate_kernel<<<N, 256, 0, stream>>>(hA, asrc, adst, iptr, csr, b2, hB, N, 4, 1);

    // -------- layer 3: hB[N,256] -> hB[N,64] (1 head, no ELU) --------
    {
        dim3 grid((N + BM - 1) / BM, 64 / BN);
        gemm_kernel<<<grid, 256, 0, stream>>>(hB, W3, hA, N, 256, 64);
    }
    alpha_kernel<<<(N + 3) / 4, 256, 0, stream>>>(hA, as3, ad3, asrc, adst, N, 1);
    aggregate_kernel<<<(N + 3) / 4, 256, 0, stream>>>(hA, asrc, adst, iptr, csr, b3, hB, N, 1, 0);

    // -------- pool + classify --------
    hipMemsetAsync(sums, 0, (size_t)G * 64 * 4, stream);
    hipMemsetAsync(cnts, 0, (size_t)G * 4, stream);
    pool_kernel<<<(N + POOL_CHUNK - 1) / POOL_CHUNK, 64, 0, stream>>>(hB, bat, sums, cnts, N);
    classify_kernel<<<1, 640, 0, stream>>>(sums, cnts, Wc, bc, out, G);
}